// Round 6
// baseline (442.445 us; speedup 1.0000x reference)
//
#include <hip/hip_runtime.h>

#define NN 2000
#define BB 8
#define P  2048   // padded dim for all MFMA operands
#define NKT 64    // K tiles of 32 for k_g4s

typedef __attribute__((ext_vector_type(8))) short bf16x8;
typedef __attribute__((ext_vector_type(4))) float f32x4;

__device__ __forceinline__ float sigf(float x) { return 1.0f / (1.0f + expf(-x)); }

__device__ __forceinline__ short f2bf(float x) {
    union { float f; unsigned u; } v; v.f = x;
    unsigned r = v.u + 0x7fffu + ((v.u >> 16) & 1u);   // round-nearest-even
    return (short)(r >> 16);
}
__device__ __forceinline__ float bf2f(short h) {
    union { unsigned u; float f; } v; v.u = ((unsigned)(unsigned short)h) << 16; return v.f;
}

__device__ __forceinline__ void gl2lds16(const short* g, short* l) {
    __builtin_amdgcn_global_load_lds(
        (const __attribute__((address_space(1))) void*)g,
        (__attribute__((address_space(3))) void*)l, 16, 0, 0);
}

// ---------------------------------------------------------------------------
// cvtW: W2/W3/adj (fp32 [2000][2000]) -> bf16 [P][P] zero-padded
// ---------------------------------------------------------------------------
__global__ __launch_bounds__(256) void k_cvtW(
    const float* __restrict__ s0, const float* __restrict__ s1, const float* __restrict__ s2,
    short* __restrict__ d0, short* __restrict__ d1, short* __restrict__ d2)
{
    const int i = blockIdx.x, sel = blockIdx.y, t = threadIdx.x;
    const float* s = (sel == 0) ? s0 : (sel == 1) ? s1 : s2;
    short* d = ((sel == 0) ? d0 : (sel == 1) ? d1 : d2) + ((size_t)i) * P + t * 8;
    bf16x8 v;
#pragma unroll
    for (int e = 0; e < 8; ++e) v[e] = 0;
    if (i < NN && t < 250) {
        const float* p = s + (size_t)i * NN + t * 8;
        float4 x0 = *(const float4*)p;
        float4 x1 = *(const float4*)(p + 4);
        float a[8] = {x0.x,x0.y,x0.z,x0.w,x1.x,x1.y,x1.z,x1.w};
#pragma unroll
        for (int e = 0; e < 8; ++e) v[e] = f2bf(a[e]);
    }
    *(bf16x8*)d = v;
}

// ---------------------------------------------------------------------------
// cvtD1: one block per row i, all 8 batches from ONE windd-row read.
// ---------------------------------------------------------------------------
__global__ __launch_bounds__(256) void k_cvtD1(
    const float* __restrict__ windd, const float* __restrict__ inputs, short* __restrict__ d1bf)
{
    const int i = blockIdx.x, t = threadIdx.x;
    const bool live = (i < NN) && (t < 250);
    float a[8];
    if (live) {
        const float* p = windd + (size_t)i * NN + t * 8;
        float4 x0 = *(const float4*)p;
        float4 x1 = *(const float4*)(p + 4);
        a[0]=x0.x; a[1]=x0.y; a[2]=x0.z; a[3]=x0.w;
        a[4]=x1.x; a[5]=x1.y; a[6]=x1.z; a[7]=x1.w;
    }
#pragma unroll
    for (int b = 0; b < BB; ++b) {
        bf16x8 v;
#pragma unroll
        for (int e = 0; e < 8; ++e) v[e] = 0;
        if (live) {
            const float wn = inputs[(size_t)b * 3 * NN + 2 * NN + i] * 360.0f;
#pragma unroll
            for (int e = 0; e < 8; ++e) {
                float dd = fabsf(a[e] - wn);
                dd = (dd > 360.0f) ? 180.0f : dd;
                float c = __cosf(dd * 0.01745329251994329577f);
                v[e] = f2bf(fmaxf(c, 0.0f));
            }
        }
        *(bf16x8*)(d1bf + ((size_t)b * P + i) * P + t * 8) = v;
    }
}

// ---------------------------------------------------------------------------
// k_g4s: wind GEMM. 256x256 tile, 8 waves (2M x 4N), BK=32, FOUR LDS slots
// (4 x 32KB), 2 phases/K-tile, stage K-tile kt+3 (A at ph0, B at ph1),
// uniform vmcnt(8) => every load waited >=4 phases after issue.
// LDS rows 64B, chunk swizzle pos ^= (row>>2)&3 (16B granules, conflict-free).
// m_bf[b] = bf16(relu(d1[b]@W2^T + b2 + adjW3) + I), [P][P] zero-padded.
// ---------------------------------------------------------------------------
__global__ __launch_bounds__(512, 2) void k_g4s(
    const short* __restrict__ d1bf, const short* __restrict__ W2bf,
    const float* __restrict__ b2, const short* __restrict__ adjw,
    short* __restrict__ m_bf)
{
    __shared__ char smem[131072];   // A slots: [4][256][64B] at 0; B slots at +65536
    const int t = threadIdx.x;
    const int w = t >> 6, lane = t & 63;
    const int wm = w >> 2, wn = w & 3;
    const int lr = lane & 15, lq = lane >> 4;
    const int tile = blockIdx.x;               // 0..63
    const int b = blockIdx.y;
    const int i0 = (tile & 7) * 256;           // same-XCD blocks share A-panel
    const int j0 = (tile >> 3) * 256;
    const short* A  = d1bf + (size_t)b * P * P;
    const short* Bm = W2bf;

    // ---- staging geometry: chunk c (16B) -> row c>>2, pos c&3,
    //      global k-granule = pos ^ ((row>>2)&3) ----
    const int cA0 = w * 64 + lane, cA1 = cA0 + 512;
    const int rA0 = cA0 >> 2, rA1 = cA1 >> 2;
    const short* srcA0 = A + (size_t)(i0 + rA0) * P + (((cA0 & 3) ^ ((rA0 >> 2) & 3)) * 8);
    const short* srcA1 = A + (size_t)(i0 + rA1) * P + (((cA1 & 3) ^ ((rA1 >> 2) & 3)) * 8);
    const short* srcB0 = Bm + (size_t)(j0 + rA0) * P + (((cA0 & 3) ^ ((rA0 >> 2) & 3)) * 8);
    const short* srcB1 = Bm + (size_t)(j0 + rA1) * P + (((cA1 & 3) ^ ((rA1 >> 2) & 3)) * 8);

#define STAGE_A(slot, ktI) do {                                                   \
        gl2lds16(srcA0 + (ktI) * 32, (short*)(smem + (slot) * 16384 + w * 1024)); \
        gl2lds16(srcA1 + (ktI) * 32, (short*)(smem + (slot) * 16384 + 8192 + w * 1024)); } while (0)
#define STAGE_B(slot, ktI) do {                                                   \
        gl2lds16(srcB0 + (ktI) * 32, (short*)(smem + 65536 + (slot) * 16384 + w * 1024)); \
        gl2lds16(srcB1 + (ktI) * 32, (short*)(smem + 65536 + (slot) * 16384 + 8192 + w * 1024)); } while (0)

    // ---- fragment read offsets: byte = row*64 + ((lq ^ (lr>>2))<<4) ----
    const int fch = (lq ^ (lr >> 2)) << 4;
    const int arowB = (wm * 128 + lr) * 64 + fch;   // + m*1024
    const int browB = (wn * 64 + lr) * 64 + fch;    // + n*1024

    f32x4 acc[8][4];
#pragma unroll
    for (int m = 0; m < 8; ++m)
#pragma unroll
        for (int n = 0; n < 4; ++n) acc[m][n] = (f32x4){0.f, 0.f, 0.f, 0.f};
    bf16x8 aF[4], bF[4];

    // ---- prologue: stage kt=0,1,2 into slots 0,1,2; full drain ----
    STAGE_A(0, 0); STAGE_B(0, 0);
    STAGE_A(1, 1); STAGE_B(1, 1);
    STAGE_A(2, 2); STAGE_B(2, 2);
    asm volatile("s_waitcnt vmcnt(0)" ::: "memory");
    __builtin_amdgcn_s_barrier();
    asm volatile("" ::: "memory");

#define MFMA_(a_, b_, m, n) acc[m][n] = __builtin_amdgcn_mfma_f32_16x16x32_bf16(a_, b_, acc[m][n], 0, 0, 0)
#define PHASE_MID()                                      \
    __builtin_amdgcn_s_barrier();                        \
    asm volatile("s_waitcnt lgkmcnt(0)" ::: "memory");   \
    __builtin_amdgcn_sched_barrier(0);                   \
    __builtin_amdgcn_s_setprio(1)
#define PHASE_TAIL()                                     \
    __builtin_amdgcn_s_setprio(0);                       \
    __builtin_amdgcn_sched_barrier(0);                   \
    asm volatile("s_waitcnt vmcnt(8)" ::: "memory");     \
    __builtin_amdgcn_s_barrier();                        \
    asm volatile("" ::: "memory")

    for (int kt = 0; kt < NKT; ++kt) {
        char* curA = smem + (kt & 3) * 16384;
        char* curB = smem + 65536 + (kt & 3) * 16384;
        const int stgSlot = (kt + 3) & 3;
        const int stgKt = (kt + 3 < NKT) ? (kt + 3) : (NKT - 1);  // clamped: never read

        // ---------- phase 0: read A m0-3 + B n0-3; stage A(kt+3); mfma m0-3 x n0-3 ----------
#pragma unroll
        for (int m = 0; m < 4; ++m) aF[m] = *(const bf16x8*)(curA + arowB + m * 1024);
#pragma unroll
        for (int n = 0; n < 4; ++n) bF[n] = *(const bf16x8*)(curB + browB + n * 1024);
        STAGE_A(stgSlot, stgKt);
        PHASE_MID();
#pragma unroll
        for (int m = 0; m < 4; ++m)
#pragma unroll
            for (int n = 0; n < 4; ++n) MFMA_(aF[m], bF[n], m, n);
        PHASE_TAIL();

        // ---------- phase 1: read A m4-7; stage B(kt+3); mfma m4-7 x n0-3 ----------
#pragma unroll
        for (int m = 0; m < 4; ++m) aF[m] = *(const bf16x8*)(curA + arowB + (m + 4) * 1024);
        STAGE_B(stgSlot, stgKt);
        PHASE_MID();
#pragma unroll
        for (int m = 0; m < 4; ++m)
#pragma unroll
            for (int n = 0; n < 4; ++n) MFMA_(aF[m], bF[n], m + 4, n);
        PHASE_TAIL();
    }
    asm volatile("s_waitcnt vmcnt(0)" ::: "memory");   // drain dummy tail stages

    // ---- epilogue: C/D frag layout col = lane&15, row = (lane>>4)*4 + q ----
    const int rbase = i0 + wm * 128 + lq * 4;
    const int cbase = j0 + wn * 64 + lr;
#pragma unroll
    for (int m = 0; m < 8; ++m) {
#pragma unroll
        for (int n = 0; n < 4; ++n) {
            const int col = cbase + n * 16;
#pragma unroll
            for (int q = 0; q < 4; ++q) {
                const int row = rbase + m * 16 + q;
                short o = 0;
                if (row < NN && col < NN) {
                    float x = acc[m][n][q] + b2[col] + bf2f(adjw[(size_t)row * NN + col]);
                    x = fmaxf(x, 0.0f);
                    if (row == col) x += 1.0f;
                    o = f2bf(x);
                }
                m_bf[((size_t)b * P + row) * P + col] = o;
            }
        }
    }
#undef MFMA_
#undef PHASE_MID
#undef PHASE_TAIL
#undef STAGE_A
#undef STAGE_B
}

// ---------------------------------------------------------------------------
// m97-style 128x128 MFMA GEMM (GEMM0 and the K-split aggregations)
// EPI 0: adjW3bf = bf16(acc + b3[col])
// EPI 2: part[kt][b][row][col<OUTD] = acc (raw), K range [kt*512, +512)
// ---------------------------------------------------------------------------
template<int EPI, int OUTD>
__global__ __launch_bounds__(256) void k_mfma(
    const short* __restrict__ Abase, const short* __restrict__ Bbase,
    const float* __restrict__ bias, const short* __restrict__ adjw,
    void* __restrict__ Cout, float* __restrict__ part, size_t aBatch)
{
    __shared__ short shA[4096];
    __shared__ short shB[4096];
    const int t = threadIdx.x;
    const int w = t >> 6, lane = t & 63;
    const int wr = w >> 1, wc = w & 1;

    int i0, j0, b, kt = 0;
    if (EPI == 2) {
        i0 = blockIdx.x * 128; j0 = 0; kt = blockIdx.y; b = blockIdx.z;
    } else {
        i0 = blockIdx.x * 128; j0 = blockIdx.y * 128; b = 0;
    }
    const int kb = (EPI == 2) ? kt * (P / 4) : 0;
    const int ke = (EPI == 2) ? kt * (P / 4) + (P / 4) : P;

    const short* A  = Abase + (size_t)b * aBatch;
    const short* Bm = Bbase + ((EPI == 2) ? (size_t)b * 128 * P : (size_t)0);

    f32x4 acc[4][4];
#pragma unroll
    for (int m = 0; m < 4; ++m)
#pragma unroll
        for (int n = 0; n < 4; ++n) acc[m][n] = (f32x4){0.f, 0.f, 0.f, 0.f};

    const int lidx0 = w * 128 + lane;
    const int lidx1 = lidx0 + 64;
    const short* aS0 = A  + (size_t)(i0 + (lidx0 >> 2)) * P + (lidx0 & 3) * 8;
    const short* aS1 = A  + (size_t)(i0 + (lidx1 >> 2)) * P + (lidx1 & 3) * 8;
    const short* bS0 = Bm + (size_t)(j0 + (lidx0 >> 2)) * P + (lidx0 & 3) * 8;
    const short* bS1 = Bm + (size_t)(j0 + (lidx1 >> 2)) * P + (lidx1 & 3) * 8;
    short* ldA0 = shA + (w * 128) * 8;
    short* ldA1 = shA + (w * 128 + 64) * 8;
    short* ldB0 = shB + (w * 128) * 8;
    short* ldB1 = shB + (w * 128 + 64) * 8;

    const int lr = lane & 15, lq = lane >> 4;
    const int aoff = (wr * 64 + lr) * 32 + lq * 8;
    const int boff = (wc * 64 + lr) * 32 + lq * 8;

    for (int k0 = kb; k0 < ke; k0 += 32) {
        gl2lds16(aS0 + k0, ldA0);
        gl2lds16(aS1 + k0, ldA1);
        gl2lds16(bS0 + k0, ldB0);
        gl2lds16(bS1 + k0, ldB1);
        __syncthreads();
        bf16x8 aF[4], bF[4];
#pragma unroll
        for (int m = 0; m < 4; ++m) aF[m] = *(const bf16x8*)(shA + aoff + m * 512);
#pragma unroll
        for (int n = 0; n < 4; ++n) bF[n] = *(const bf16x8*)(shB + boff + n * 512);
#pragma unroll
        for (int m = 0; m < 4; ++m)
#pragma unroll
            for (int n = 0; n < 4; ++n)
                acc[m][n] = __builtin_amdgcn_mfma_f32_16x16x32_bf16(aF[m], bF[n], acc[m][n], 0, 0, 0);
        __syncthreads();
    }

    const int rbase = i0 + wr * 64 + lq * 4;
    const int cbase = j0 + wc * 64 + lr;
#pragma unroll
    for (int m = 0; m < 4; ++m) {
#pragma unroll
        for (int n = 0; n < 4; ++n) {
            const int col = cbase + n * 16;
#pragma unroll
            for (int q = 0; q < 4; ++q) {
                const int row = rbase + m * 16 + q;
                float v = acc[m][n][q];
                if (EPI == 0) {
                    if (row < NN && col < NN)
                        ((short*)Cout)[(size_t)row * NN + col] = f2bf(v + bias[col]);
                } else {
                    if (row < NN && col < OUTD)
                        part[((size_t)(kt * BB + b) * NN + row) * OUTD + col] = v;
                }
            }
        }
    }
}

// combine 4 K-split partials (fixed order = deterministic)
template<int OUTD>
__global__ __launch_bounds__(256) void k_comb(
    const float* __restrict__ part, const float* __restrict__ dinv,
    const float* __restrict__ bias, float* __restrict__ out)
{
    const size_t idx = (size_t)blockIdx.x * 256 + threadIdx.x;
    const size_t S = (size_t)BB * NN * OUTD;
    if (idx >= S) return;
    const int o = (int)(idx % OUTD);
    const size_t r = idx / OUTD;
    const int i = (int)(r % NN);
    const int b = (int)(r / NN);
    float s = ((part[idx] + part[idx + S]) + (part[idx + 2 * S] + part[idx + 3 * S]));
    out[idx] = s * dinv[b * NN + i] + bias[o];
}

// dinv[b,i] = rsqrt(sum_j m_bf[b][i][j])
__global__ __launch_bounds__(256) void k_rowsum_bf(const short* __restrict__ m_bf, float* __restrict__ dinv)
{
    const int i = blockIdx.x, b = blockIdx.y;
    const short* p = m_bf + ((size_t)b * P + i) * P + threadIdx.x * 8;
    bf16x8 v = *(const bf16x8*)p;
    float s = 0.0f;
#pragma unroll
    for (int e = 0; e < 8; ++e) s += bf2f(v[e]);
#pragma unroll
    for (int off = 32; off > 0; off >>= 1) s += __shfl_down(s, off);
    __shared__ float red[4];
    if ((threadIdx.x & 63) == 0) red[threadIdx.x >> 6] = s;
    __syncthreads();
    if (threadIdx.x == 0) dinv[b * NN + i] = rsqrtf(red[0] + red[1] + red[2] + red[3]);
}

// zT[b][o][j] = bf16( dinv[b,j] * sum_c x[b,j,c]*W[o,c] )
template<int OUT>
__global__ __launch_bounds__(128) void k_xwT(
    const float* __restrict__ inputs, const float* __restrict__ hsrc,
    const float* __restrict__ W, const float* __restrict__ dinv, short* __restrict__ zT)
{
    const int b = blockIdx.y;
    const int j0 = blockIdx.x * 16;
    const int t = threadIdx.x;
    __shared__ float wl[128 * 65];
    __shared__ float xs[16 * 66];
    __shared__ float dj[16];
    for (int idx = t; idx < OUT * 65; idx += 128) wl[idx] = W[idx];
    for (int idx = t; idx < 16 * 64; idx += 128) {
        int jj = idx >> 6, hh = idx & 63, j = j0 + jj;
        xs[jj * 66 + 1 + hh] = (j < NN) ? hsrc[((size_t)b * NN + j) * 64 + hh] : 0.0f;
    }
    if (t < 16) {
        int j = j0 + t;
        xs[t * 66] = (j < NN) ? inputs[(size_t)b * 3 * NN + j] : 0.0f;
        dj[t] = (j < NN) ? dinv[b * NN + j] : 0.0f;
    }
    __syncthreads();
    for (int jj = 0; jj < 16; ++jj) {
        float a = 0.0f;
        if (t < OUT) {
            const float* xr = &xs[jj * 66];
            const float* wr = &wl[t * 65];
#pragma unroll
            for (int c = 0; c < 65; ++c) a = fmaf(xr[c], wr[c], a);
        }
        int j = j0 + jj;
        zT[((size_t)b * 128 + t) * P + j] = (t < OUT && j < NN) ? f2bf(a * dj[jj]) : (short)0;
    }
}

__global__ __launch_bounds__(256) void k_chred(const float* __restrict__ conc,
                                               float* __restrict__ avg, float* __restrict__ mx)
{
    const int bc = blockIdx.x;
    const float* p = conc + (size_t)bc * NN;
    float s = 0.0f, mv = -3.402823466e+38f;
    for (int n = threadIdx.x; n < NN; n += 256) { float v = p[n]; s += v; mv = fmaxf(mv, v); }
#pragma unroll
    for (int off = 32; off > 0; off >>= 1) {
        s += __shfl_down(s, off);
        mv = fmaxf(mv, __shfl_down(mv, off));
    }
    __shared__ float rs[4], rm[4];
    if ((threadIdx.x & 63) == 0) { rs[threadIdx.x >> 6] = s; rm[threadIdx.x >> 6] = mv; }
    __syncthreads();
    if (threadIdx.x == 0) {
        avg[bc] = (rs[0] + rs[1] + rs[2] + rs[3]) * (1.0f / NN);
        mx[bc]  = fmaxf(fmaxf(rm[0], rm[1]), fmaxf(rm[2], rm[3]));
    }
}

__global__ __launch_bounds__(128) void k_ca(
    const float* __restrict__ avg, const float* __restrict__ mx,
    const float* __restrict__ Wca1, const float* __restrict__ Wca2, float* __restrict__ ca)
{
    const int b = blockIdx.x, t = threadIdx.x;
    __shared__ float av[128], mv[128], h[16];
    av[t] = avg[b * 128 + t];
    mv[t] = mx[b * 128 + t];
    __syncthreads();
    if (t < 16) {
        int o8 = t & 7;
        const float* src = (t < 8) ? av : mv;
        float s = 0.0f;
        for (int c = 0; c < 128; ++c) s = fmaf(Wca1[o8 * 128 + c], src[c], s);
        h[t] = fmaxf(s, 0.0f);
    }
    __syncthreads();
    float s = 0.0f;
#pragma unroll
    for (int k = 0; k < 8; ++k) s = fmaf(Wca2[t * 8 + k], h[k] + h[8 + k], s);
    ca[b * 128 + t] = sigf(s);
}

// fused spatial-attention (halo recompute) + GRU gates
__global__ __launch_bounds__(256) void k_satgate(
    const float* __restrict__ conc, const float* __restrict__ ca,
    const float* __restrict__ Wsa, const float* __restrict__ hidden,
    float* __restrict__ rh, float* __restrict__ u)
{
    const int b = blockIdx.y;
    const int n0 = blockIdx.x * 256;
    const int t = threadIdx.x;
    __shared__ float cas[128];
    __shared__ float wsa[14];
    __shared__ float s0l[262], s1l[262];
    if (t < 128) cas[t] = ca[b * 128 + t];
    if (t >= 128 && t < 142) wsa[t - 128] = Wsa[t - 128];
    __syncthreads();

    const float* cb = conc + (size_t)b * NN * 128;
    // main column n0+t -> index t+3
    {
        const int n = n0 + t;
        float sm = 0.0f, sx = -3.402823466e+38f;
        if (n < NN) {
            for (int c = 0; c < 128; ++c) {
                float v = cas[c] * cb[(size_t)c * NN + n];
                sm += v; sx = fmaxf(sx, v);
            }
            s0l[t + 3] = sm * (1.0f / 128.0f);
            s1l[t + 3] = sx;
        } else { s0l[t + 3] = 0.0f; s1l[t + 3] = 0.0f; }
    }
    // halo columns: t=0..2 -> n0-3+t (idx t); t=3..5 -> n0+256+(t-3) (idx 256+t)
    if (t < 6) {
        const int hn = (t < 3) ? (n0 - 3 + t) : (n0 + 256 + (t - 3));
        const int hi = (t < 3) ? t : (256 + t);
        float sm = 0.0f, sx = -3.402823466e+38f;
        if (hn >= 0 && hn < NN) {
            for (int c = 0; c < 128; ++c) {
                float v = cas[c] * cb[(size_t)c * NN + hn];
                sm += v; sx = fmaxf(sx, v);
            }
            s0l[hi] = sm * (1.0f / 128.0f);
            s1l[hi] = sx;
        } else { s0l[hi] = 0.0f; s1l[hi] = 0.0f; }
    }
    __syncthreads();

    const int n = n0 + t;
    if (n >= NN) return;
    float sa = 0.0f;
#pragma unroll
    for (int k = 0; k < 7; ++k)
        sa += wsa[k] * s0l[t + k] + wsa[7 + k] * s1l[t + k];
    float gs = sigf(sa);
    for (int c = 0; c < 128; ++c) {
        float v = gs * cas[c] * cb[(size_t)c * NN + n];
        float g = sigf(v);
        if (c < 64)
            rh[(size_t)b * NN * 64 + (size_t)c * NN + n] =
                g * hidden[(size_t)b * NN * 64 + (size_t)c * NN + n];
        else
            u[(size_t)b * NN * 64 + (size_t)(c - 64) * NN + n] = g;
    }
}

__global__ __launch_bounds__(256) void k_fin(
    const float* __restrict__ u, const float* __restrict__ hidden,
    const float* __restrict__ cpre, float* __restrict__ out)
{
    const size_t idx = (size_t)blockIdx.x * 256 + threadIdx.x;
    if (idx >= (size_t)BB * NN * 64) return;
    float uu = u[idx];
    out[idx] = uu * hidden[idx] + (1.0f - uu) * tanhf(cpre[idx]);
}

extern "C" void kernel_launch(void* const* d_in, const int* in_sizes, int n_in,
                              void* d_out, int out_size, void* d_ws, size_t ws_size,
                              hipStream_t stream)
{
    (void)in_sizes; (void)n_in; (void)out_size; (void)ws_size;
    const float* inputs = (const float*)d_in[0];
    const float* hidden = (const float*)d_in[1];
    const float* adj    = (const float*)d_in[2];
    const float* windd  = (const float*)d_in[3];
    const float* W2     = (const float*)d_in[4];
    const float* b2     = (const float*)d_in[5];
    const float* W3     = (const float*)d_in[6];
    const float* b3     = (const float*)d_in[7];
    const float* W1a    = (const float*)d_in[8];
    const float* b1a    = (const float*)d_in[9];
    const float* W1b    = (const float*)d_in[10];
    const float* b1b    = (const float*)d_in[11];
    const float* Wca1   = (const float*)d_in[12];
    const float* Wca2   = (const float*)d_in[13];
    const float* Wsa    = (const float*)d_in[14];
    float* out = (float*)d_out;

    // ---- workspace layout (byte offsets; unions by lifetime) ----
    char* W = (char*)d_ws;
    short* adjW3bf = (short*)(W + 0);
    short* W2bf    = (short*)(W + 8000000);
    short* W3bf    = (short*)(W + 16388608);
    short* adjbf   = (short*)(W + 24777216);
    short* m_bf    = (short*)(W + 16388608);     // union with {W3bf, adjbf}
    char* D = W + 83497472;
    short* d1bf = (short*)D;                     // union with post-GEMM1 buffers
    float* dinv = (float*)(D + 0);
    float* avgb = (float*)(D + 64000);
    float* mxb  = (float*)(D + 68096);
    float* cab  = (float*)(D + 72192);
    short* zT   = (short*)(D + 204800);
    float* conc = (float*)(D + 4399104);
    float* rh   = (float*)(D + 12591104);
    float* ubuf = (float*)(D + 16687104);
    float* cpre = (float*)(D + 20783104);
    float* part = (float*)(D + 24879104);

    const size_t PP = (size_t)P * P;

    k_cvtW<<<dim3(P, 3), 256, 0, stream>>>(W2, W3, adj, W2bf, W3bf, adjbf);
    k_cvtD1<<<P, 256, 0, stream>>>(windd, inputs, d1bf);
    k_mfma<0, 0><<<dim3(16, 16, 1), 256, 0, stream>>>(adjbf, W3bf, b3, nullptr, adjW3bf, nullptr, 0);
    k_g4s<<<dim3(64, BB), 512, 0, stream>>>(d1bf, W2bf, b2, adjW3bf, m_bf);
    k_rowsum_bf<<<dim3(NN, BB), 256, 0, stream>>>(m_bf, dinv);
    k_xwT<128><<<dim3(128, BB), 128, 0, stream>>>(inputs, hidden, W1a, dinv, zT);
    k_mfma<2, 128><<<dim3(16, 4, BB), 256, 0, stream>>>(m_bf, zT, nullptr, nullptr, nullptr, part, PP);
    k_comb<128><<<(BB * NN * 128 + 255) / 256, 256, 0, stream>>>(part, dinv, b1a, conc);
    k_chred<<<BB * 128, 256, 0, stream>>>(conc, avgb, mxb);
    k_ca<<<BB, 128, 0, stream>>>(avgb, mxb, Wca1, Wca2, cab);
    k_satgate<<<dim3(8, BB), 256, 0, stream>>>(conc, cab, Wsa, hidden, rh, ubuf);
    k_xwT<64><<<dim3(128, BB), 128, 0, stream>>>(inputs, rh, W1b, dinv, zT);
    k_mfma<2, 64><<<dim3(16, 4, BB), 256, 0, stream>>>(m_bf, zT, nullptr, nullptr, nullptr, part, PP);
    k_comb<64><<<(BB * NN * 64 + 255) / 256, 256, 0, stream>>>(part, dinv, b1b, cpre);
    k_fin<<<(BB * NN * 64 + 255) / 256, 256, 0, stream>>>(ubuf, hidden, cpre, out);
}

// Round 7
// 420.017 us; speedup vs baseline: 1.0534x; 1.0534x over previous
//
#include <hip/hip_runtime.h>

#define NN 2000
#define BB 8
#define P  2048   // padded dim for all MFMA operands
#define NIT 32    // K iterations of 64 for k_gd

typedef __attribute__((ext_vector_type(8))) short bf16x8;
typedef __attribute__((ext_vector_type(4))) float f32x4;

__device__ __forceinline__ float sigf(float x) { return 1.0f / (1.0f + expf(-x)); }

__device__ __forceinline__ short f2bf(float x) {
    union { float f; unsigned u; } v; v.f = x;
    unsigned r = v.u + 0x7fffu + ((v.u >> 16) & 1u);   // round-nearest-even
    return (short)(r >> 16);
}
__device__ __forceinline__ float bf2f(short h) {
    union { unsigned u; float f; } v; v.u = ((unsigned)(unsigned short)h) << 16; return v.f;
}

__device__ __forceinline__ void gl2lds16(const short* g, short* l) {
    __builtin_amdgcn_global_load_lds(
        (const __attribute__((address_space(1))) void*)g,
        (__attribute__((address_space(3))) void*)l, 16, 0, 0);
}

// ---------------------------------------------------------------------------
// cvtW: W2/W3/adj (fp32 [2000][2000]) -> bf16 [P][P] zero-padded
// ---------------------------------------------------------------------------
__global__ __launch_bounds__(256) void k_cvtW(
    const float* __restrict__ s0, const float* __restrict__ s1, const float* __restrict__ s2,
    short* __restrict__ d0, short* __restrict__ d1, short* __restrict__ d2)
{
    const int i = blockIdx.x, sel = blockIdx.y, t = threadIdx.x;
    const float* s = (sel == 0) ? s0 : (sel == 1) ? s1 : s2;
    short* d = ((sel == 0) ? d0 : (sel == 1) ? d1 : d2) + ((size_t)i) * P + t * 8;
    bf16x8 v;
#pragma unroll
    for (int e = 0; e < 8; ++e) v[e] = 0;
    if (i < NN && t < 250) {
        const float* p = s + (size_t)i * NN + t * 8;
        float4 x0 = *(const float4*)p;
        float4 x1 = *(const float4*)(p + 4);
        float a[8] = {x0.x,x0.y,x0.z,x0.w,x1.x,x1.y,x1.z,x1.w};
#pragma unroll
        for (int e = 0; e < 8; ++e) v[e] = f2bf(a[e]);
    }
    *(bf16x8*)d = v;
}

// ---------------------------------------------------------------------------
// cvtD1: one block per row i, all 8 batches from ONE windd-row read.
// ---------------------------------------------------------------------------
__global__ __launch_bounds__(256) void k_cvtD1(
    const float* __restrict__ windd, const float* __restrict__ inputs, short* __restrict__ d1bf)
{
    const int i = blockIdx.x, t = threadIdx.x;
    const bool live = (i < NN) && (t < 250);
    float a[8];
    if (live) {
        const float* p = windd + (size_t)i * NN + t * 8;
        float4 x0 = *(const float4*)p;
        float4 x1 = *(const float4*)(p + 4);
        a[0]=x0.x; a[1]=x0.y; a[2]=x0.z; a[3]=x0.w;
        a[4]=x1.x; a[5]=x1.y; a[6]=x1.z; a[7]=x1.w;
    }
#pragma unroll
    for (int b = 0; b < BB; ++b) {
        bf16x8 v;
#pragma unroll
        for (int e = 0; e < 8; ++e) v[e] = 0;
        if (live) {
            const float wn = inputs[(size_t)b * 3 * NN + 2 * NN + i] * 360.0f;
#pragma unroll
            for (int e = 0; e < 8; ++e) {
                float dd = fabsf(a[e] - wn);
                dd = (dd > 360.0f) ? 180.0f : dd;
                float c = __cosf(dd * 0.01745329251994329577f);
                v[e] = f2bf(fmaxf(c, 0.0f));
            }
        }
        *(bf16x8*)(d1bf + ((size_t)b * P + i) * P + t * 8) = v;
    }
}

// ---------------------------------------------------------------------------
// k_gd: wind GEMM. 256x256 tile, 8 waves (2M x 4N), BK=64, TWO LDS slots
// (2 x 64KB), ONE barrier + ONE vmcnt(0) per K-iteration (classic dbuf).
// LDS rows 128B with the PROVEN conflict-free swizzle: k-granule g of row r
// stored at byte r*128 + (g ^ (r&7))*16 (both-sides via pre-swizzled global
// source, linear global_load_lds dest).
// m_bf[b] = bf16(relu(d1[b]@W2^T + b2 + adjW3) + I), [P][P] zero-padded.
// ---------------------------------------------------------------------------
__global__ __launch_bounds__(512, 2) void k_gd(
    const short* __restrict__ d1bf, const short* __restrict__ W2bf,
    const float* __restrict__ b2, const short* __restrict__ adjw,
    short* __restrict__ m_bf)
{
    __shared__ char smem[131072];   // A slots: [2][256][128B] at 0; B slots at +65536
    const int t = threadIdx.x;
    const int w = t >> 6, lane = t & 63;
    const int wm = w >> 2, wn = w & 3;
    const int lr = lane & 15, lq = lane >> 4;
    const int tile = blockIdx.x;               // 0..63
    const int b = blockIdx.y;
    const int i0 = (tile & 7) * 256;           // same-XCD blocks share A-panel
    const int j0 = (tile >> 3) * 256;
    const short* A  = d1bf + (size_t)b * P * P;
    const short* Bm = W2bf;

    // ---- staging geometry: round q covers chunks c = q*512 + t ----
    // c -> row r = c>>3, pos p = c&7, global k-granule g = p ^ (r&7)
    const short* srcA[4];
    const short* srcB[4];
#pragma unroll
    for (int q = 0; q < 4; ++q) {
        const int c = q * 512 + t;
        const int r = c >> 3;
        const int g = (c & 7) ^ (r & 7);
        srcA[q] = A  + (size_t)(i0 + r) * P + g * 8;
        srcB[q] = Bm + (size_t)(j0 + r) * P + g * 8;
    }

#define STAGE_A(slot, ktI) do {                                                        \
        gl2lds16(srcA[0] + (ktI) * 64, (short*)(smem + (slot) * 32768 + (w * 64) * 16));          \
        gl2lds16(srcA[1] + (ktI) * 64, (short*)(smem + (slot) * 32768 + (512 + w * 64) * 16));    \
        gl2lds16(srcA[2] + (ktI) * 64, (short*)(smem + (slot) * 32768 + (1024 + w * 64) * 16));   \
        gl2lds16(srcA[3] + (ktI) * 64, (short*)(smem + (slot) * 32768 + (1536 + w * 64) * 16)); } while (0)
#define STAGE_B(slot, ktI) do {                                                        \
        gl2lds16(srcB[0] + (ktI) * 64, (short*)(smem + 65536 + (slot) * 32768 + (w * 64) * 16));          \
        gl2lds16(srcB[1] + (ktI) * 64, (short*)(smem + 65536 + (slot) * 32768 + (512 + w * 64) * 16));    \
        gl2lds16(srcB[2] + (ktI) * 64, (short*)(smem + 65536 + (slot) * 32768 + (1024 + w * 64) * 16));   \
        gl2lds16(srcB[3] + (ktI) * 64, (short*)(smem + 65536 + (slot) * 32768 + (1536 + w * 64) * 16)); } while (0)

    // ---- fragment read offsets (proven conflict-free pattern) ----
    // frag row = base + f*16 + lr (128B rows); k-gran = ks*4+lq; byte XOR (lr&7)<<4
    const int fx0 = (lq << 4) ^ ((lr & 7) << 4);          // ks=0
    const int fx1 = ((4 + lq) << 4) ^ ((lr & 7) << 4);    // ks=1
    const int arowB = (wm * 128 + lr) * 128;              // + m*2048
    const int browB = (wn * 64 + lr) * 128;               // + n*2048

    f32x4 acc[8][4];
#pragma unroll
    for (int m = 0; m < 8; ++m)
#pragma unroll
        for (int n = 0; n < 4; ++n) acc[m][n] = (f32x4){0.f, 0.f, 0.f, 0.f};
    bf16x8 aF[4][2], bF[4][2];

    // ---- prologue: stage kt=0 into slot 0, full drain ----
    STAGE_A(0, 0);
    STAGE_B(0, 0);
    asm volatile("s_waitcnt vmcnt(0)" ::: "memory");
    __builtin_amdgcn_s_barrier();
    asm volatile("" ::: "memory");

#define MFMA_(a_, b_, m, n) acc[m][n] = __builtin_amdgcn_mfma_f32_16x16x32_bf16(a_, b_, acc[m][n], 0, 0, 0)

    for (int kt = 0; kt < NIT; ++kt) {
        char* curA = smem + (kt & 1) * 32768;
        char* curB = smem + 65536 + (kt & 1) * 32768;
        const int stgSlot = (kt + 1) & 1;
        const int stgKt = (kt + 1 < NIT) ? (kt + 1) : (NIT - 1);  // clamped: never read

        // ---------- phase A: read A m0-3 + B n0-3; stage A(kt+1); 32 MFMA ----------
#pragma unroll
        for (int m = 0; m < 4; ++m) {
            aF[m][0] = *(const bf16x8*)(curA + arowB + m * 2048 + fx0);
            aF[m][1] = *(const bf16x8*)(curA + arowB + m * 2048 + fx1);
        }
#pragma unroll
        for (int n = 0; n < 4; ++n) {
            bF[n][0] = *(const bf16x8*)(curB + browB + n * 2048 + fx0);
            bF[n][1] = *(const bf16x8*)(curB + browB + n * 2048 + fx1);
        }
        STAGE_A(stgSlot, stgKt);
        asm volatile("s_waitcnt lgkmcnt(0)" ::: "memory");
        __builtin_amdgcn_sched_barrier(0);
        __builtin_amdgcn_s_setprio(1);
#pragma unroll
        for (int m = 0; m < 4; ++m)
#pragma unroll
            for (int n = 0; n < 4; ++n) {
                MFMA_(aF[m][0], bF[n][0], m, n);
                MFMA_(aF[m][1], bF[n][1], m, n);
            }
        __builtin_amdgcn_s_setprio(0);

        // ---------- phase B: read A m4-7; stage B(kt+1); 32 MFMA ----------
#pragma unroll
        for (int m = 0; m < 4; ++m) {
            aF[m][0] = *(const bf16x8*)(curA + arowB + (m + 4) * 2048 + fx0);
            aF[m][1] = *(const bf16x8*)(curA + arowB + (m + 4) * 2048 + fx1);
        }
        STAGE_B(stgSlot, stgKt);
        asm volatile("s_waitcnt lgkmcnt(0)" ::: "memory");
        __builtin_amdgcn_sched_barrier(0);
        __builtin_amdgcn_s_setprio(1);
#pragma unroll
        for (int m = 0; m < 4; ++m)
#pragma unroll
            for (int n = 0; n < 4; ++n) {
                MFMA_(aF[m][0], bF[n][0], m + 4, n);
                MFMA_(aF[m][1], bF[n][1], m + 4, n);
            }
        __builtin_amdgcn_s_setprio(0);

        // ---------- iter end: certify stage(kt+1) complete, then ONE barrier ----------
        asm volatile("s_waitcnt vmcnt(0)" ::: "memory");
        __builtin_amdgcn_s_barrier();
        asm volatile("" ::: "memory");
    }

    // ---- epilogue: C/D frag layout col = lane&15, row = (lane>>4)*4 + q ----
    const int rbase = i0 + wm * 128 + lq * 4;
    const int cbase = j0 + wn * 64 + lr;
#pragma unroll
    for (int m = 0; m < 8; ++m) {
#pragma unroll
        for (int n = 0; n < 4; ++n) {
            const int col = cbase + n * 16;
#pragma unroll
            for (int q = 0; q < 4; ++q) {
                const int row = rbase + m * 16 + q;
                short o = 0;
                if (row < NN && col < NN) {
                    float x = acc[m][n][q] + b2[col] + bf2f(adjw[(size_t)row * NN + col]);
                    x = fmaxf(x, 0.0f);
                    if (row == col) x += 1.0f;
                    o = f2bf(x);
                }
                m_bf[((size_t)b * P + row) * P + col] = o;
            }
        }
    }
#undef MFMA_
#undef STAGE_A
#undef STAGE_B
}

// ---------------------------------------------------------------------------
// m97-style 128x128 MFMA GEMM (GEMM0 and the K-split aggregations)
// EPI 0: adjW3bf = bf16(acc + b3[col])
// EPI 2: part[kt][b][row][col<OUTD] = acc (raw), K range [kt*512, +512)
// ---------------------------------------------------------------------------
template<int EPI, int OUTD>
__global__ __launch_bounds__(256) void k_mfma(
    const short* __restrict__ Abase, const short* __restrict__ Bbase,
    const float* __restrict__ bias, const short* __restrict__ adjw,
    void* __restrict__ Cout, float* __restrict__ part, size_t aBatch)
{
    __shared__ short shA[4096];
    __shared__ short shB[4096];
    const int t = threadIdx.x;
    const int w = t >> 6, lane = t & 63;
    const int wr = w >> 1, wc = w & 1;

    int i0, j0, b, kt = 0;
    if (EPI == 2) {
        i0 = blockIdx.x * 128; j0 = 0; kt = blockIdx.y; b = blockIdx.z;
    } else {
        i0 = blockIdx.x * 128; j0 = blockIdx.y * 128; b = 0;
    }
    const int kb = (EPI == 2) ? kt * (P / 4) : 0;
    const int ke = (EPI == 2) ? kt * (P / 4) + (P / 4) : P;

    const short* A  = Abase + (size_t)b * aBatch;
    const short* Bm = Bbase + ((EPI == 2) ? (size_t)b * 128 * P : (size_t)0);

    f32x4 acc[4][4];
#pragma unroll
    for (int m = 0; m < 4; ++m)
#pragma unroll
        for (int n = 0; n < 4; ++n) acc[m][n] = (f32x4){0.f, 0.f, 0.f, 0.f};

    const int lidx0 = w * 128 + lane;
    const int lidx1 = lidx0 + 64;
    const short* aS0 = A  + (size_t)(i0 + (lidx0 >> 2)) * P + (lidx0 & 3) * 8;
    const short* aS1 = A  + (size_t)(i0 + (lidx1 >> 2)) * P + (lidx1 & 3) * 8;
    const short* bS0 = Bm + (size_t)(j0 + (lidx0 >> 2)) * P + (lidx0 & 3) * 8;
    const short* bS1 = Bm + (size_t)(j0 + (lidx1 >> 2)) * P + (lidx1 & 3) * 8;
    short* ldA0 = shA + (w * 128) * 8;
    short* ldA1 = shA + (w * 128 + 64) * 8;
    short* ldB0 = shB + (w * 128) * 8;
    short* ldB1 = shB + (w * 128 + 64) * 8;

    const int lr = lane & 15, lq = lane >> 4;
    const int aoff = (wr * 64 + lr) * 32 + lq * 8;
    const int boff = (wc * 64 + lr) * 32 + lq * 8;

    for (int k0 = kb; k0 < ke; k0 += 32) {
        gl2lds16(aS0 + k0, ldA0);
        gl2lds16(aS1 + k0, ldA1);
        gl2lds16(bS0 + k0, ldB0);
        gl2lds16(bS1 + k0, ldB1);
        __syncthreads();
        bf16x8 aF[4], bF[4];
#pragma unroll
        for (int m = 0; m < 4; ++m) aF[m] = *(const bf16x8*)(shA + aoff + m * 512);
#pragma unroll
        for (int n = 0; n < 4; ++n) bF[n] = *(const bf16x8*)(shB + boff + n * 512);
#pragma unroll
        for (int m = 0; m < 4; ++m)
#pragma unroll
            for (int n = 0; n < 4; ++n)
                acc[m][n] = __builtin_amdgcn_mfma_f32_16x16x32_bf16(aF[m], bF[n], acc[m][n], 0, 0, 0);
        __syncthreads();
    }

    const int rbase = i0 + wr * 64 + lq * 4;
    const int cbase = j0 + wc * 64 + lr;
#pragma unroll
    for (int m = 0; m < 4; ++m) {
#pragma unroll
        for (int n = 0; n < 4; ++n) {
            const int col = cbase + n * 16;
#pragma unroll
            for (int q = 0; q < 4; ++q) {
                const int row = rbase + m * 16 + q;
                float v = acc[m][n][q];
                if (EPI == 0) {
                    if (row < NN && col < NN)
                        ((short*)Cout)[(size_t)row * NN + col] = f2bf(v + bias[col]);
                } else {
                    if (row < NN && col < OUTD)
                        part[((size_t)(kt * BB + b) * NN + row) * OUTD + col] = v;
                }
            }
        }
    }
}

// combine 4 K-split partials (fixed order = deterministic)
template<int OUTD>
__global__ __launch_bounds__(256) void k_comb(
    const float* __restrict__ part, const float* __restrict__ dinv,
    const float* __restrict__ bias, float* __restrict__ out)
{
    const size_t idx = (size_t)blockIdx.x * 256 + threadIdx.x;
    const size_t S = (size_t)BB * NN * OUTD;
    if (idx >= S) return;
    const int o = (int)(idx % OUTD);
    const size_t r = idx / OUTD;
    const int i = (int)(r % NN);
    const int b = (int)(r / NN);
    float s = ((part[idx] + part[idx + S]) + (part[idx + 2 * S] + part[idx + 3 * S]));
    out[idx] = s * dinv[b * NN + i] + bias[o];
}

// dinv[b,i] = rsqrt(sum_j m_bf[b][i][j])
__global__ __launch_bounds__(256) void k_rowsum_bf(const short* __restrict__ m_bf, float* __restrict__ dinv)
{
    const int i = blockIdx.x, b = blockIdx.y;
    const short* p = m_bf + ((size_t)b * P + i) * P + threadIdx.x * 8;
    bf16x8 v = *(const bf16x8*)p;
    float s = 0.0f;
#pragma unroll
    for (int e = 0; e < 8; ++e) s += bf2f(v[e]);
#pragma unroll
    for (int off = 32; off > 0; off >>= 1) s += __shfl_down(s, off);
    __shared__ float red[4];
    if ((threadIdx.x & 63) == 0) red[threadIdx.x >> 6] = s;
    __syncthreads();
    if (threadIdx.x == 0) dinv[b * NN + i] = rsqrtf(red[0] + red[1] + red[2] + red[3]);
}

// zT[b][o][j] = bf16( dinv[b,j] * sum_c x[b,j,c]*W[o,c] )
template<int OUT>
__global__ __launch_bounds__(128) void k_xwT(
    const float* __restrict__ inputs, const float* __restrict__ hsrc,
    const float* __restrict__ W, const float* __restrict__ dinv, short* __restrict__ zT)
{
    const int b = blockIdx.y;
    const int j0 = blockIdx.x * 16;
    const int t = threadIdx.x;
    __shared__ float wl[128 * 65];
    __shared__ float xs[16 * 66];
    __shared__ float dj[16];
    for (int idx = t; idx < OUT * 65; idx += 128) wl[idx] = W[idx];
    for (int idx = t; idx < 16 * 64; idx += 128) {
        int jj = idx >> 6, hh = idx & 63, j = j0 + jj;
        xs[jj * 66 + 1 + hh] = (j < NN) ? hsrc[((size_t)b * NN + j) * 64 + hh] : 0.0f;
    }
    if (t < 16) {
        int j = j0 + t;
        xs[t * 66] = (j < NN) ? inputs[(size_t)b * 3 * NN + j] : 0.0f;
        dj[t] = (j < NN) ? dinv[b * NN + j] : 0.0f;
    }
    __syncthreads();
    for (int jj = 0; jj < 16; ++jj) {
        float a = 0.0f;
        if (t < OUT) {
            const float* xr = &xs[jj * 66];
            const float* wr = &wl[t * 65];
#pragma unroll
            for (int c = 0; c < 65; ++c) a = fmaf(xr[c], wr[c], a);
        }
        int j = j0 + jj;
        zT[((size_t)b * 128 + t) * P + j] = (t < OUT && j < NN) ? f2bf(a * dj[jj]) : (short)0;
    }
}

__global__ __launch_bounds__(256) void k_chred(const float* __restrict__ conc,
                                               float* __restrict__ avg, float* __restrict__ mx)
{
    const int bc = blockIdx.x;
    const float* p = conc + (size_t)bc * NN;
    float s = 0.0f, mv = -3.402823466e+38f;
    for (int n = threadIdx.x; n < NN; n += 256) { float v = p[n]; s += v; mv = fmaxf(mv, v); }
#pragma unroll
    for (int off = 32; off > 0; off >>= 1) {
        s += __shfl_down(s, off);
        mv = fmaxf(mv, __shfl_down(mv, off));
    }
    __shared__ float rs[4], rm[4];
    if ((threadIdx.x & 63) == 0) { rs[threadIdx.x >> 6] = s; rm[threadIdx.x >> 6] = mv; }
    __syncthreads();
    if (threadIdx.x == 0) {
        avg[bc] = (rs[0] + rs[1] + rs[2] + rs[3]) * (1.0f / NN);
        mx[bc]  = fmaxf(fmaxf(rm[0], rm[1]), fmaxf(rm[2], rm[3]));
    }
}

__global__ __launch_bounds__(128) void k_ca(
    const float* __restrict__ avg, const float* __restrict__ mx,
    const float* __restrict__ Wca1, const float* __restrict__ Wca2, float* __restrict__ ca)
{
    const int b = blockIdx.x, t = threadIdx.x;
    __shared__ float av[128], mv[128], h[16];
    av[t] = avg[b * 128 + t];
    mv[t] = mx[b * 128 + t];
    __syncthreads();
    if (t < 16) {
        int o8 = t & 7;
        const float* src = (t < 8) ? av : mv;
        float s = 0.0f;
        for (int c = 0; c < 128; ++c) s = fmaf(Wca1[o8 * 128 + c], src[c], s);
        h[t] = fmaxf(s, 0.0f);
    }
    __syncthreads();
    float s = 0.0f;
#pragma unroll
    for (int k = 0; k < 8; ++k) s = fmaf(Wca2[t * 8 + k], h[k] + h[8 + k], s);
    ca[b * 128 + t] = sigf(s);
}

// fused spatial-attention (halo recompute) + GRU gates
__global__ __launch_bounds__(256) void k_satgate(
    const float* __restrict__ conc, const float* __restrict__ ca,
    const float* __restrict__ Wsa, const float* __restrict__ hidden,
    float* __restrict__ rh, float* __restrict__ u)
{
    const int b = blockIdx.y;
    const int n0 = blockIdx.x * 256;
    const int t = threadIdx.x;
    __shared__ float cas[128];
    __shared__ float wsa[14];
    __shared__ float s0l[262], s1l[262];
    if (t < 128) cas[t] = ca[b * 128 + t];
    if (t >= 128 && t < 142) wsa[t - 128] = Wsa[t - 128];
    __syncthreads();

    const float* cb = conc + (size_t)b * NN * 128;
    {
        const int n = n0 + t;
        float sm = 0.0f, sx = -3.402823466e+38f;
        if (n < NN) {
            for (int c = 0; c < 128; ++c) {
                float v = cas[c] * cb[(size_t)c * NN + n];
                sm += v; sx = fmaxf(sx, v);
            }
            s0l[t + 3] = sm * (1.0f / 128.0f);
            s1l[t + 3] = sx;
        } else { s0l[t + 3] = 0.0f; s1l[t + 3] = 0.0f; }
    }
    if (t < 6) {
        const int hn = (t < 3) ? (n0 - 3 + t) : (n0 + 256 + (t - 3));
        const int hi = (t < 3) ? t : (256 + t);
        float sm = 0.0f, sx = -3.402823466e+38f;
        if (hn >= 0 && hn < NN) {
            for (int c = 0; c < 128; ++c) {
                float v = cas[c] * cb[(size_t)c * NN + hn];
                sm += v; sx = fmaxf(sx, v);
            }
            s0l[hi] = sm * (1.0f / 128.0f);
            s1l[hi] = sx;
        } else { s0l[hi] = 0.0f; s1l[hi] = 0.0f; }
    }
    __syncthreads();

    const int n = n0 + t;
    if (n >= NN) return;
    float sa = 0.0f;
#pragma unroll
    for (int k = 0; k < 7; ++k)
        sa += wsa[k] * s0l[t + k] + wsa[7 + k] * s1l[t + k];
    float gs = sigf(sa);
    for (int c = 0; c < 128; ++c) {
        float v = gs * cas[c] * cb[(size_t)c * NN + n];
        float g = sigf(v);
        if (c < 64)
            rh[(size_t)b * NN * 64 + (size_t)c * NN + n] =
                g * hidden[(size_t)b * NN * 64 + (size_t)c * NN + n];
        else
            u[(size_t)b * NN * 64 + (size_t)(c - 64) * NN + n] = g;
    }
}

__global__ __launch_bounds__(256) void k_fin(
    const float* __restrict__ u, const float* __restrict__ hidden,
    const float* __restrict__ cpre, float* __restrict__ out)
{
    const size_t idx = (size_t)blockIdx.x * 256 + threadIdx.x;
    if (idx >= (size_t)BB * NN * 64) return;
    float uu = u[idx];
    out[idx] = uu * hidden[idx] + (1.0f - uu) * tanhf(cpre[idx]);
}

extern "C" void kernel_launch(void* const* d_in, const int* in_sizes, int n_in,
                              void* d_out, int out_size, void* d_ws, size_t ws_size,
                              hipStream_t stream)
{
    (void)in_sizes; (void)n_in; (void)out_size; (void)ws_size;
    const float* inputs = (const float*)d_in[0];
    const float* hidden = (const float*)d_in[1];
    const float* adj    = (const float*)d_in[2];
    const float* windd  = (const float*)d_in[3];
    const float* W2     = (const float*)d_in[4];
    const float* b2     = (const float*)d_in[5];
    const float* W3     = (const float*)d_in[6];
    const float* b3     = (const float*)d_in[7];
    const float* W1a    = (const float*)d_in[8];
    const float* b1a    = (const float*)d_in[9];
    const float* W1b    = (const float*)d_in[10];
    const float* b1b    = (const float*)d_in[11];
    const float* Wca1   = (const float*)d_in[12];
    const float* Wca2   = (const float*)d_in[13];
    const float* Wsa    = (const float*)d_in[14];
    float* out = (float*)d_out;

    // ---- workspace layout (byte offsets; unions by lifetime) ----
    char* W = (char*)d_ws;
    short* adjW3bf = (short*)(W + 0);
    short* W2bf    = (short*)(W + 8000000);
    short* W3bf    = (short*)(W + 16388608);
    short* adjbf   = (short*)(W + 24777216);
    short* m_bf    = (short*)(W + 16388608);     // union with {W3bf, adjbf}
    char* D = W + 83497472;
    short* d1bf = (short*)D;                     // union with post-GEMM1 buffers
    float* dinv = (float*)(D + 0);
    float* avgb = (float*)(D + 64000);
    float* mxb  = (float*)(D + 68096);
    float* cab  = (float*)(D + 72192);
    short* zT   = (short*)(D + 204800);
    float* conc = (float*)(D + 4399104);
    float* rh   = (float*)(D + 12591104);
    float* ubuf = (float*)(D + 16687104);
    float* cpre = (float*)(D + 20783104);
    float* part = (float*)(D + 24879104);

    const size_t PP = (size_t)P * P;

    k_cvtW<<<dim3(P, 3), 256, 0, stream>>>(W2, W3, adj, W2bf, W3bf, adjbf);
    k_cvtD1<<<P, 256, 0, stream>>>(windd, inputs, d1bf);
    k_mfma<0, 0><<<dim3(16, 16, 1), 256, 0, stream>>>(adjbf, W3bf, b3, nullptr, adjW3bf, nullptr, 0);
    k_gd<<<dim3(64, BB), 512, 0, stream>>>(d1bf, W2bf, b2, adjW3bf, m_bf);
    k_rowsum_bf<<<dim3(NN, BB), 256, 0, stream>>>(m_bf, dinv);
    k_xwT<128><<<dim3(128, BB), 128, 0, stream>>>(inputs, hidden, W1a, dinv, zT);
    k_mfma<2, 128><<<dim3(16, 4, BB), 256, 0, stream>>>(m_bf, zT, nullptr, nullptr, nullptr, part, PP);
    k_comb<128><<<(BB * NN * 128 + 255) / 256, 256, 0, stream>>>(part, dinv, b1a, conc);
    k_chred<<<BB * 128, 256, 0, stream>>>(conc, avgb, mxb);
    k_ca<<<BB, 128, 0, stream>>>(avgb, mxb, Wca1, Wca2, cab);
    k_satgate<<<dim3(8, BB), 256, 0, stream>>>(conc, cab, Wsa, hidden, rh, ubuf);
    k_xwT<64><<<dim3(128, BB), 128, 0, stream>>>(inputs, rh, W1b, dinv, zT);
    k_mfma<2, 64><<<dim3(16, 4, BB), 256, 0, stream>>>(m_bf, zT, nullptr, nullptr, nullptr, part, PP);
    k_comb<64><<<(BB * NN * 64 + 255) / 256, 256, 0, stream>>>(part, dinv, b1b, cpre);
    k_fin<<<(BB * NN * 64 + 255) / 256, 256, 0, stream>>>(ubuf, hidden, cpre, out);
}